// Round 10
// baseline (471.748 us; speedup 1.0000x reference)
//
#include <hip/hip_runtime.h>
#include <hip/hip_fp16.h>
#include <math.h>
#include <stdint.h>

#define B_ 4
#define N_ 512
#define D_ 64
#define NDIAG (2 * N_ - 1)   // 1023 diagonal rows of D
#define WV 4                 // waves per block
#define K_ 16                // diagonals per chunk (between barriers)
#define DC0 9                // chunk stagger between adjacent waves
#define NCH 40               // chunks per wave
#define CTOT (DC0 * (WV - 1) + NCH)  // 67
#define RING 1028            // non-wrapping ring: one slot per diagonal
#define BIGF 1e30f           // finite border sentinel (absorbs garbage d)

typedef unsigned int uint32x4 __attribute__((ext_vector_type(4)));

// Phase 1: D[b][i][j] = ||x[b,i]-y[b,j]|| in FP16, group-packed layout:
// dd2 halves at ((b*256+g)*256 + j2)*8 + (r%4)*2 + (j%2), where r=i+j, g=r/4,
// j2=j/2. One 16B lane-load then serves 4 diagonal rows x 2 columns.
__global__ __launch_bounds__(256) void dist_h_kernel(
    const float* __restrict__ x, const float* __restrict__ y,
    __half* __restrict__ dd2)
{
    const int b = blockIdx.z;
    const int i0 = blockIdx.y * 16;
    const int j0 = blockIdx.x * 16;
    __shared__ float xs[16 * 68];
    __shared__ float ys[16 * 68];
    const int t = threadIdx.x;
    const int lr = t >> 4;
    const int lc = t & 15;
    const float4* xsrc = (const float4*)(x + (((size_t)b * N_) + i0 + lr) * D_);
    const float4* ysrc = (const float4*)(y + (((size_t)b * N_) + j0 + lr) * D_);
    *(float4*)(&xs[lr * 68 + lc * 4]) = xsrc[lc];
    *(float4*)(&ys[lr * 68 + lc * 4]) = ysrc[lc];
    __syncthreads();

    const int ti = t >> 4, tj = t & 15;
    const float* xr = &xs[ti * 68];
    const float* yr = &ys[tj * 68];
    float acc = 0.f;
#pragma unroll
    for (int k = 0; k < 16; ++k) {
        float4 a = *(const float4*)(xr + 4 * k);
        float4 c = *(const float4*)(yr + 4 * k);
        float d0 = a.x - c.x, d1 = a.y - c.y, d2 = a.z - c.z, d3 = a.w - c.w;
        acc += d0 * d0 + d1 * d1 + d2 * d2 + d3 * d3;
    }
    const int i = i0 + ti, j = j0 + tj;
    const int r = i + j, g = r >> 2, rs = r & 3, j2 = j >> 1, p = j & 1;
    dd2[(((((size_t)b << 8) | g) << 8) | j2) * 8 + rs * 2 + p] =
        __float2half(sqrtf(acc));
}

__device__ __forceinline__ float dpp_shr1(float x) {
    int v = __builtin_amdgcn_update_dpp(0x7f800000, __float_as_int(x),
                                        0x138 /*WAVE_SHR1*/, 0xf, 0xf, false);
    return __int_as_float(v);
}

__device__ __forceinline__ float vmin3(float a, float b, float c) {
    float r; asm("v_min3_f32 %0, %1, %2, %3" : "=v"(r) : "v"(a), "v"(b), "v"(c)); return r;
}
__device__ __forceinline__ float vmed3(float a, float b, float c) {
    float r; asm("v_med3_f32 %0, %1, %2, %3" : "=v"(r) : "v"(a), "v"(b), "v"(c)); return r;
}
__device__ __forceinline__ float vmax3(float a, float b, float c) {
    float r; asm("v_max3_f32 %0, %1, %2, %3" : "=v"(r) : "v"(a), "v"(b), "v"(c)); return r;
}

#if __has_builtin(__builtin_amdgcn_exp2f)
#define EXP2(x) __builtin_amdgcn_exp2f(x)
#else
#define EXP2(x) exp2f(x)
#endif
#if __has_builtin(__builtin_amdgcn_logf)
#define LOG2(x) __builtin_amdgcn_logf(x)
#else
#define LOG2(x) log2f(x)
#endif

__device__ __forceinline__ float2 h2f(unsigned u) {
    union { unsigned u; __half2 h; } cv; cv.u = u;
    return __half22float2(cv.h);
}

// Staggered soft-DTW body. MAIN: ring + d_out writes (exact). !MAIN: probe
// (no ring, dumps to ws), repeated REP times for top-5 visibility.
// d-transport: 4 x global_load_dwordx4 per chunk (fp16, 4 rows/load),
// named-scalar queue, 2 chunks ahead, exact counted vmcnt.
template <bool MAIN, int REP>
__device__ __forceinline__ void sdtw_body(
    const __half* __restrict__ dd2, float* __restrict__ out,
    float* __restrict__ dump, int b, int tid)
{
    const int w = tid >> 6;
    const int lane = tid & 63;

    if constexpr (MAIN) {
        for (int q = tid; q < N_; q += 256) {
            out[b * N_ + q] = (float)q;
            out[B_ * N_ + b * N_ + q] = (float)q;
        }
    }

    __shared__ __align__(16) float ring[WV + 1][RING];
    for (int q = tid; q < (WV + 1) * RING; q += 256)
        (&ring[0][0])[q] = (q == 0) ? 0.0f : BIGF;
    asm volatile("s_waitcnt vmcnt(0)");  // drain path stores: clean vmcnt
    __syncthreads();

    const float C1 = 14.4269504089f;    // (1/gamma)*log2(e)
    const float C2 = -0.069314718056f;  // -gamma*ln(2)
    const int c0w = DC0 * w;
    const int s0w = 128 * w + 2;
    const bool l0 = (lane == 0);
    const bool l63 = (lane == 63);
    const float* ringR = ring[w];
    float* ringW = ring[w + 1];
    // byte addr of group g for this lane: wbase + (4*lc+gi)*4096
    const uint64_t wbase = (uint64_t)dd2 + ((uint64_t)b << 20)
                         + (uint64_t)(64 * w + lane) * 16
                         + ((uint64_t)(32 * w) << 12);
    float res = 0.0f;

    for (int rep = 0; rep < REP; ++rep) {
        unsigned u0 = (unsigned)(-(2 * lane));
        float rA0 = BIGF, rB0 = BIGF, rA1 = BIGF;
        float lnL = BIGF, ldL = BIGF;

        uint32x4 qb0_0{}, qb0_1{}, qb0_2{}, qb0_3{};
        uint32x4 qb1_0{}, qb1_1{}, qb1_2{}, qb1_3{};
        uint32x4 qb2_0{}, qb2_1{}, qb2_2{}, qb2_3{};

#define ISSUE4(lcn_, b_)                                                    \
    {                                                                       \
        const uint64_t g0_ = wbase + ((uint64_t)((lcn_) * 4) << 12);        \
        asm volatile("global_load_dwordx4 %0, %1, off"                      \
                     : "=v"(qb##b_##_0) : "v"(g0_));                        \
        asm volatile("global_load_dwordx4 %0, %1, off"                      \
                     : "=v"(qb##b_##_1) : "v"(g0_ + 4096));                 \
        asm volatile("global_load_dwordx4 %0, %1, off"                      \
                     : "=v"(qb##b_##_2) : "v"(g0_ + 8192));                 \
        asm volatile("global_load_dwordx4 %0, %1, off"                      \
                     : "=v"(qb##b_##_3) : "v"(g0_ + 12288));                \
    }

#define TIE4(b_)                                                            \
    asm volatile("" : "+v"(qb##b_##_0), "+v"(qb##b_##_1),                   \
                      "+v"(qb##b_##_2), "+v"(qb##b_##_3));

#define STEP(d0_, d1_, tt_, rrn_)                                           \
    {                                                                       \
        float m0  = vmin3(rA0, lnL, ldL);                                   \
        float md0 = vmed3(rA0, lnL, ldL);                                   \
        float mx0 = vmax3(rA0, lnL, ldL);                                   \
        float e0 = EXP2((m0 - md0) * C1);                                   \
        float f0 = EXP2((m0 - mx0) * C1);                                   \
        float r0 = fmaf(C2, LOG2(1.0f + e0 + f0), m0 + (d0_));              \
        float m1  = vmin3(rA1, rA0, rB0);                                   \
        float md1 = vmed3(rA1, rA0, rB0);                                   \
        float mx1 = vmax3(rA1, rA0, rB0);                                   \
        float e1 = EXP2((m1 - md1) * C1);                                   \
        float f1 = EXP2((m1 - mx1) * C1);                                   \
        float r1 = fmaf(C2, LOG2(1.0f + e1 + f1), m1 + (d1_));              \
        res = (u0 == 512u) ? r1 : res;                                      \
        u0 += 1u;                                                           \
        rB0 = rA0; rA0 = r0;                                                \
        ldL = lnL;                                                          \
        float sh = dpp_shr1(r1);                                            \
        lnL = l0 ? (rrn_) : sh;                                             \
        rA1 = r1;                                                           \
        if constexpr (MAIN) { if (l63) ringW[s0c + (tt_)] = r1; }           \
    }

#define GBLOCK(b_, gi_, t0_, rA_, rB_, rC_, rD_)                            \
    {                                                                       \
        const float2 fa_ = h2f(qb##b_##_##gi_[0]);                          \
        const float2 fb_ = h2f(qb##b_##_##gi_[1]);                          \
        const float2 fc_ = h2f(qb##b_##_##gi_[2]);                          \
        const float2 fd_ = h2f(qb##b_##_##gi_[3]);                          \
        STEP(fa_.x, fa_.y, (t0_) + 0, rA_)                                  \
        STEP(fb_.x, fb_.y, (t0_) + 1, rB_)                                  \
        STEP(fc_.x, fc_.y, (t0_) + 2, rC_)                                  \
        STEP(fd_.x, fd_.y, (t0_) + 3, rD_)                                  \
    }

#define CHUNK(b_, b2_)                                                      \
    {                                                                       \
        const int s0c = s0w + lc * K_;                                      \
        if (lc + 2 < NCH) {                                                 \
            ISSUE4(lc + 2, b2_);                                            \
            asm volatile("s_waitcnt vmcnt(8)");                             \
        } else if (lc + 1 < NCH) {                                          \
            asm volatile("s_waitcnt vmcnt(4)");                             \
        } else {                                                            \
            asm volatile("s_waitcnt vmcnt(0)");                             \
        }                                                                   \
        TIE4(b_);                                                           \
        float rr0, rr1, rr2, rr3, rr4, rr5, rr6, rr7, rr8, rr9, rr10,       \
              rr11, rr12, rr13, rr14, rr15, rr16, rr17;                     \
        if constexpr (MAIN) {                                               \
            const float4 qr0 = *(const float4*)&ringR[s0c - 2];             \
            const float4 qr1 = *(const float4*)&ringR[s0c + 2];             \
            const float4 qr2 = *(const float4*)&ringR[s0c + 6];             \
            const float4 qr3 = *(const float4*)&ringR[s0c + 10];            \
            const float2 qr4 = *(const float2*)&ringR[s0c + 14];            \
            rr0 = qr0.x; rr1 = qr0.y; rr2 = qr0.z; rr3 = qr0.w;             \
            rr4 = qr1.x; rr5 = qr1.y; rr6 = qr1.z; rr7 = qr1.w;             \
            rr8 = qr2.x; rr9 = qr2.y; rr10 = qr2.z; rr11 = qr2.w;           \
            rr12 = qr3.x; rr13 = qr3.y; rr14 = qr3.z; rr15 = qr3.w;         \
            rr16 = qr4.x; rr17 = qr4.y;                                     \
        } else {                                                            \
            rr0 = rr1 = rr2 = rr3 = rr4 = rr5 = rr6 = rr7 = rr8 = rr9 =     \
            rr10 = rr11 = rr12 = rr13 = rr14 = rr15 = rr16 = rr17 = BIGF;   \
        }                                                                   \
        if (lc == 0) {                                                      \
            lnL = l0 ? rr1 : BIGF;                                          \
            ldL = l0 ? rr0 : BIGF;                                          \
        }                                                                   \
        GBLOCK(b_, 0, 0,  rr2,  rr3,  rr4,  rr5)                            \
        GBLOCK(b_, 1, 4,  rr6,  rr7,  rr8,  rr9)                            \
        GBLOCK(b_, 2, 8,  rr10, rr11, rr12, rr13)                           \
        GBLOCK(b_, 3, 12, rr14, rr15, rr16, rr17)                           \
    }

        if (w == 0) { ISSUE4(0, 0); ISSUE4(1, 1); }  // wave-0 prologue

        for (int c = 0; c < CTOT; ++c) {
            const int lc = c - c0w;
            if (lc >= 0 && lc < NCH) {
                switch (lc % 3) {
                    case 0: { CHUNK(0, 2) } break;
                    case 1: { CHUNK(1, 0) } break;
                    default: { CHUNK(2, 1) } break;
                }
            } else if (lc == -2) {
                ISSUE4(0, 0);
            } else if (lc == -1) {
                ISSUE4(1, 1);
            }
            // LDS-only drain + barrier (d-loads stay in flight)
            asm volatile("s_waitcnt lgkmcnt(0)" ::: "memory");
            __builtin_amdgcn_s_barrier();
        }
#undef CHUNK
#undef GBLOCK
#undef STEP
#undef TIE4
#undef ISSUE4
    }

    if constexpr (MAIN) {
        if (w == WV - 1 && l63) out[2 * B_ * N_ + b] = res;
    } else {
        asm volatile("" :: "v"(res));
        if (w == WV - 1 && l63) dump[b] = res;
    }
}

__global__ __launch_bounds__(256, 1) void sdtw_h4_kernel(
    const __half* __restrict__ dd2, float* __restrict__ out)
{
    sdtw_body<true, 1>(dd2, out, nullptr, blockIdx.x, threadIdx.x);
}

// probe: new load stream + chain, no ring, x4 repeat (top-5-visible)
__global__ __launch_bounds__(256, 1) void probe_loads_kernel(
    const __half* __restrict__ dd2, float* __restrict__ dump)
{
    sdtw_body<false, 4>(dd2, nullptr, dump, blockIdx.x, threadIdx.x);
}

extern "C" void kernel_launch(void* const* d_in, const int* in_sizes, int n_in,
                              void* d_out, int out_size, void* d_ws, size_t ws_size,
                              hipStream_t stream) {
    const float* x = (const float*)d_in[0];
    const float* y = (const float*)d_in[1];
    float* out = (float*)d_out;
    __half* dd2 = (__half*)d_ws;                          // 4 MB fp16 packed
    float* dump = (float*)((char*)d_ws + (6u << 20));     // probe dump (ws)

    dim3 g1(N_ / 16, N_ / 16, B_);
    dist_h_kernel<<<g1, 256, 0, stream>>>(x, y, dd2);
    sdtw_h4_kernel<<<B_, 256, 0, stream>>>(dd2, out);     // exact output
    probe_loads_kernel<<<B_, 256, 0, stream>>>(dd2, dump);
}

// Round 12
// 129.310 us; speedup vs baseline: 3.6482x; 3.6482x over previous
//
#include <hip/hip_runtime.h>
#include <hip/hip_fp16.h>
#include <math.h>
#include <stdint.h>

#define B_ 4
#define N_ 512
#define D_ 64
#define NDIAG (2 * N_ - 1)   // 1023 diagonal rows of D
#define WV 4                 // waves per block
#define K_ 32                // diagonals per chunk
#define DC0 6                // chunk stagger between waves (ring lag 4 + margin 2)
#define NCH 20               // chunks per wave (640 diagonals)
#define CTOT (DC0 * (WV - 1) + NCH)  // 38 intervals
#define RING 1028
#define BIGF 1e30f

typedef unsigned int uint32x4 __attribute__((ext_vector_type(4)));

// Phase 1: D in FP16, group-packed: half idx = ((b*256+g)*256 + j2)*8 + rs*2+p
// (r=i+j, g=r/4, rs=r%4, j2=j/2, p=j%2) -> one 16B lane-load = 4 rows x 2 cols.
__global__ __launch_bounds__(256) void dist_h_kernel(
    const float* __restrict__ x, const float* __restrict__ y,
    __half* __restrict__ dd2)
{
    const int b = blockIdx.z;
    const int i0 = blockIdx.y * 16;
    const int j0 = blockIdx.x * 16;
    __shared__ float xs[16 * 68];
    __shared__ float ys[16 * 68];
    const int t = threadIdx.x;
    const int lr = t >> 4;
    const int lc = t & 15;
    const float4* xsrc = (const float4*)(x + (((size_t)b * N_) + i0 + lr) * D_);
    const float4* ysrc = (const float4*)(y + (((size_t)b * N_) + j0 + lr) * D_);
    *(float4*)(&xs[lr * 68 + lc * 4]) = xsrc[lc];
    *(float4*)(&ys[lr * 68 + lc * 4]) = ysrc[lc];
    __syncthreads();

    const int ti = t >> 4, tj = t & 15;
    const float* xr = &xs[ti * 68];
    const float* yr = &ys[tj * 68];
    float acc = 0.f;
#pragma unroll
    for (int k = 0; k < 16; ++k) {
        float4 a = *(const float4*)(xr + 4 * k);
        float4 c = *(const float4*)(yr + 4 * k);
        float d0 = a.x - c.x, d1 = a.y - c.y, d2 = a.z - c.z, d3 = a.w - c.w;
        acc += d0 * d0 + d1 * d1 + d2 * d2 + d3 * d3;
    }
    const int i = i0 + ti, j = j0 + tj;
    const int r = i + j, g = r >> 2, rs = r & 3, j2 = j >> 1, p = j & 1;
    dd2[(((((size_t)b << 8) | g) << 8) | j2) * 8 + rs * 2 + p] =
        __float2half(sqrtf(acc));
}

__device__ __forceinline__ float dpp_shr1(float x) {
    int v = __builtin_amdgcn_update_dpp(0x7f800000, __float_as_int(x),
                                        0x138 /*WAVE_SHR1*/, 0xf, 0xf, false);
    return __int_as_float(v);
}
__device__ __forceinline__ float vmin3(float a, float b, float c) {
    float r; asm("v_min3_f32 %0, %1, %2, %3" : "=v"(r) : "v"(a), "v"(b), "v"(c)); return r;
}
__device__ __forceinline__ float vmed3(float a, float b, float c) {
    float r; asm("v_med3_f32 %0, %1, %2, %3" : "=v"(r) : "v"(a), "v"(b), "v"(c)); return r;
}
__device__ __forceinline__ float vmax3(float a, float b, float c) {
    float r; asm("v_max3_f32 %0, %1, %2, %3" : "=v"(r) : "v"(a), "v"(b), "v"(c)); return r;
}
#if __has_builtin(__builtin_amdgcn_exp2f)
#define EXP2(x) __builtin_amdgcn_exp2f(x)
#else
#define EXP2(x) exp2f(x)
#endif
#if __has_builtin(__builtin_amdgcn_logf)
#define LOG2(x) __builtin_amdgcn_logf(x)
#else
#define LOG2(x) log2f(x)
#endif
__device__ __forceinline__ float2 h2f(unsigned u) {
    union { unsigned u; __half2 h; } cv; cv.u = u;
    return __half22float2(cv.h);
}

// Phase 2: R10's PROVEN schedule (issue-at-start, 3 buffers, counted vmcnt,
// barrier EVERY interval) with only K changed 16->32: 38 intervals vs 67,
// same total load count (160 dwordx4/wave). Bisect experiment: per-interval
// cost -> ~55us; per-load cost -> ~90us.
__global__ __launch_bounds__(256, 1) void sdtw_k32b_kernel(
    const __half* __restrict__ dd2, float* __restrict__ out)
{
    const int b = blockIdx.x;
    const int tid = threadIdx.x;
    const int w = tid >> 6;
    const int lane = tid & 63;

    for (int q = tid; q < N_; q += 256) {
        out[b * N_ + q] = (float)q;
        out[B_ * N_ + b * N_ + q] = (float)q;
    }

    __shared__ __align__(16) float ring[WV + 1][RING];
    for (int q = tid; q < (WV + 1) * RING; q += 256)
        (&ring[0][0])[q] = (q == 0) ? 0.0f : BIGF;
    asm volatile("s_waitcnt vmcnt(0)");  // drain path stores: clean vmcnt
    __syncthreads();

    const float C1 = 14.4269504089f;    // (1/gamma)*log2(e)
    const float C2 = -0.069314718056f;  // -gamma*ln(2)
    const int c0w = DC0 * w;
    const int s0w = 128 * w + 2;
    const bool l0 = (lane == 0);
    const bool l63 = (lane == 63);
    const float* ringR = ring[w];
    float* ringW = ring[w + 1];
    // byte addr of group cell: wbase + (8*lc + gi)*4096
    const uint64_t wbase = (uint64_t)dd2 + ((uint64_t)b << 20)
                         + (uint64_t)(64 * w + lane) * 16
                         + ((uint64_t)(32 * w) << 12);

    unsigned u0 = (unsigned)(-(2 * lane));
    float rA0 = BIGF, rB0 = BIGF, rA1 = BIGF;
    float lnL = BIGF, ldL = BIGF;
    float res = 0.0f;

    // 24 named dwordx4 quads: 3 buffers x 8 groups (96 VGPRs)
#define DECLQ(b_)                                                           \
    uint32x4 qb##b_##_0{}, qb##b_##_1{}, qb##b_##_2{}, qb##b_##_3{},        \
             qb##b_##_4{}, qb##b_##_5{}, qb##b_##_6{}, qb##b_##_7{};
    DECLQ(0) DECLQ(1) DECLQ(2)

#define LD1(qv_, a_)                                                        \
    asm volatile("global_load_dwordx4 %0, %1, off" : "=v"(qv_) : "v"(a_));

#define ISSUE8(lcn_, b_)                                                    \
    {                                                                       \
        const uint64_t g0_ = wbase + ((uint64_t)((lcn_) * 8) << 12);        \
        LD1(qb##b_##_0, g0_)          LD1(qb##b_##_1, g0_ + 4096)           \
        LD1(qb##b_##_2, g0_ + 8192)   LD1(qb##b_##_3, g0_ + 12288)          \
        LD1(qb##b_##_4, g0_ + 16384)  LD1(qb##b_##_5, g0_ + 20480)          \
        LD1(qb##b_##_6, g0_ + 24576)  LD1(qb##b_##_7, g0_ + 28672)          \
    }

#define TIEB(b_)                                                            \
    asm volatile("" : "+v"(qb##b_##_0), "+v"(qb##b_##_1),                   \
                      "+v"(qb##b_##_2), "+v"(qb##b_##_3));                  \
    asm volatile("" : "+v"(qb##b_##_4), "+v"(qb##b_##_5),                   \
                      "+v"(qb##b_##_6), "+v"(qb##b_##_7));

#define STEP(d0_, d1_, tt_, rrn_)                                           \
    {                                                                       \
        float m0  = vmin3(rA0, lnL, ldL);                                   \
        float md0 = vmed3(rA0, lnL, ldL);                                   \
        float mx0 = vmax3(rA0, lnL, ldL);                                   \
        float e0 = EXP2((m0 - md0) * C1);                                   \
        float f0 = EXP2((m0 - mx0) * C1);                                   \
        float r0 = fmaf(C2, LOG2(1.0f + e0 + f0), m0 + (d0_));              \
        float m1  = vmin3(rA1, rA0, rB0);                                   \
        float md1 = vmed3(rA1, rA0, rB0);                                   \
        float mx1 = vmax3(rA1, rA0, rB0);                                   \
        float e1 = EXP2((m1 - md1) * C1);                                   \
        float f1 = EXP2((m1 - mx1) * C1);                                   \
        float r1 = fmaf(C2, LOG2(1.0f + e1 + f1), m1 + (d1_));              \
        res = (u0 == 512u) ? r1 : res;                                      \
        u0 += 1u;                                                           \
        rB0 = rA0; rA0 = r0;                                                \
        ldL = lnL;                                                          \
        float sh = dpp_shr1(r1);                                            \
        lnL = l0 ? (rrn_) : sh;                                             \
        rA1 = r1;                                                           \
        if (l63) ringW[s0c + (tt_)] = r1;                                   \
    }

#define GBLOCK(b_, gi_, rA_, rB_, rC_, rD_)                                 \
    {                                                                       \
        const float2 fa_ = h2f(qb##b_##_##gi_[0]);                          \
        const float2 fb_ = h2f(qb##b_##_##gi_[1]);                          \
        const float2 fc_ = h2f(qb##b_##_##gi_[2]);                          \
        const float2 fd_ = h2f(qb##b_##_##gi_[3]);                          \
        STEP(fa_.x, fa_.y, 4 * gi_ + 0, rA_)                                \
        STEP(fb_.x, fb_.y, 4 * gi_ + 1, rB_)                                \
        STEP(fc_.x, fc_.y, 4 * gi_ + 2, rC_)                                \
        STEP(fd_.x, fd_.y, 4 * gi_ + 3, rD_)                                \
    }

// R10 pattern: issue chunk lc+2 at TOP, then counted wait for chunk lc.
#define CHUNK(b_, b2_)                                                      \
    {                                                                       \
        const int s0c = s0w + lc * K_;                                      \
        if (lc + 2 < NCH) {                                                 \
            ISSUE8(lc + 2, b2_);                                            \
            asm volatile("s_waitcnt vmcnt(16)");                            \
        } else if (lc + 1 < NCH) {                                          \
            asm volatile("s_waitcnt vmcnt(8)");                             \
        } else {                                                            \
            asm volatile("s_waitcnt vmcnt(0)");                             \
        }                                                                   \
        TIEB(b_);                                                           \
        const float4 p0 = *(const float4*)&ringR[s0c - 2];                  \
        const float4 p1 = *(const float4*)&ringR[s0c + 2];                  \
        const float4 p2 = *(const float4*)&ringR[s0c + 6];                  \
        const float4 p3 = *(const float4*)&ringR[s0c + 10];                 \
        const float4 p4 = *(const float4*)&ringR[s0c + 14];                 \
        const float4 p5 = *(const float4*)&ringR[s0c + 18];                 \
        const float4 p6 = *(const float4*)&ringR[s0c + 22];                 \
        const float4 p7 = *(const float4*)&ringR[s0c + 26];                 \
        const float2 p8 = *(const float2*)&ringR[s0c + 30];                 \
        const float rr0 = p0.x, rr1 = p0.y, rr2 = p0.z, rr3 = p0.w;         \
        const float rr4 = p1.x, rr5 = p1.y, rr6 = p1.z, rr7 = p1.w;         \
        const float rr8 = p2.x, rr9 = p2.y, rr10 = p2.z, rr11 = p2.w;       \
        const float rr12 = p3.x, rr13 = p3.y, rr14 = p3.z, rr15 = p3.w;     \
        const float rr16 = p4.x, rr17 = p4.y, rr18 = p4.z, rr19 = p4.w;     \
        const float rr20 = p5.x, rr21 = p5.y, rr22 = p5.z, rr23 = p5.w;     \
        const float rr24 = p6.x, rr25 = p6.y, rr26 = p6.z, rr27 = p6.w;     \
        const float rr28 = p7.x, rr29 = p7.y, rr30 = p7.z, rr31 = p7.w;     \
        const float rr32 = p8.x, rr33 = p8.y;                               \
        if (lc == 0) {                                                      \
            lnL = l0 ? rr1 : BIGF;                                          \
            ldL = l0 ? rr0 : BIGF;                                          \
        }                                                                   \
        GBLOCK(b_, 0, rr2,  rr3,  rr4,  rr5)                                \
        GBLOCK(b_, 1, rr6,  rr7,  rr8,  rr9)                                \
        GBLOCK(b_, 2, rr10, rr11, rr12, rr13)                               \
        GBLOCK(b_, 3, rr14, rr15, rr16, rr17)                               \
        GBLOCK(b_, 4, rr18, rr19, rr20, rr21)                               \
        GBLOCK(b_, 5, rr22, rr23, rr24, rr25)                               \
        GBLOCK(b_, 6, rr26, rr27, rr28, rr29)                               \
        GBLOCK(b_, 7, rr30, rr31, rr32, rr33)                               \
    }

    if (w == 0) { ISSUE8(0, 0); ISSUE8(1, 1); }  // wave-0 prologue

    for (int c = 0; c < CTOT; ++c) {
        const int lc = c - c0w;
        if (lc >= 0 && lc < NCH) {
            switch (lc % 3) {
                case 0: { CHUNK(0, 2) } break;
                case 1: { CHUNK(1, 0) } break;
                default: { CHUNK(2, 1) } break;
            }
        } else if (lc == -2) {
            ISSUE8(0, 0);
        } else if (lc == -1) {
            ISSUE8(1, 1);
        }
        // LDS drain + barrier EVERY interval (R10-proven); d-loads in flight
        asm volatile("s_waitcnt lgkmcnt(0)" ::: "memory");
        __builtin_amdgcn_s_barrier();
    }
#undef CHUNK
#undef GBLOCK
#undef STEP
#undef TIEB
#undef ISSUE8
#undef LD1
#undef DECLQ

    // R[512][512] captured by wave 3 / lane 63 at i1 == 512
    if (w == WV - 1 && l63) out[2 * B_ * N_ + b] = res;
}

extern "C" void kernel_launch(void* const* d_in, const int* in_sizes, int n_in,
                              void* d_out, int out_size, void* d_ws, size_t ws_size,
                              hipStream_t stream) {
    const float* x = (const float*)d_in[0];
    const float* y = (const float*)d_in[1];
    float* out = (float*)d_out;
    __half* dd2 = (__half*)d_ws;  // 4 MB fp16 packed table (ws >= 8 MB)

    dim3 g1(N_ / 16, N_ / 16, B_);
    dist_h_kernel<<<g1, 256, 0, stream>>>(x, y, dd2);
    sdtw_k32b_kernel<<<B_, 256, 0, stream>>>(dd2, out);
}

// Round 15
// 120.862 us; speedup vs baseline: 3.9032x; 1.0699x over previous
//
#include <hip/hip_runtime.h>
#include <hip/hip_fp16.h>
#include <math.h>
#include <stdint.h>

#define B_ 4
#define N_ 512
#define D_ 64
#define NDIAG (2 * N_ - 1)   // 1023 diagonal rows of D
#define WV 4                 // waves per block
#define K_ 16                // diagonals per chunk (between barriers)
#define DC0 9                // chunk stagger between adjacent waves
#define NCH 40               // chunks per wave
#define CTOT (DC0 * (WV - 1) + NCH)  // 67
#define RING 1028            // non-wrapping ring: one slot per diagonal
#define BIGF 1e30f           // finite border sentinel (absorbs garbage d)

typedef unsigned int uint32x4 __attribute__((ext_vector_type(4)));

// Phase 1: D[b][i][j] = ||x[b,i]-y[b,j]|| in FP16, group-packed layout:
// dd2 halves at ((b*256+g)*256 + j2)*8 + (r%4)*2 + (j%2), where r=i+j, g=r/4,
// j2=j/2. One 16B lane-load then serves 4 diagonal rows x 2 columns.
__global__ __launch_bounds__(256) void dist_h_kernel(
    const float* __restrict__ x, const float* __restrict__ y,
    __half* __restrict__ dd2)
{
    const int b = blockIdx.z;
    const int i0 = blockIdx.y * 16;
    const int j0 = blockIdx.x * 16;
    __shared__ float xs[16 * 68];
    __shared__ float ys[16 * 68];
    const int t = threadIdx.x;
    const int lr = t >> 4;
    const int lc = t & 15;
    const float4* xsrc = (const float4*)(x + (((size_t)b * N_) + i0 + lr) * D_);
    const float4* ysrc = (const float4*)(y + (((size_t)b * N_) + j0 + lr) * D_);
    *(float4*)(&xs[lr * 68 + lc * 4]) = xsrc[lc];
    *(float4*)(&ys[lr * 68 + lc * 4]) = ysrc[lc];
    __syncthreads();

    const int ti = t >> 4, tj = t & 15;
    const float* xr = &xs[ti * 68];
    const float* yr = &ys[tj * 68];
    float acc = 0.f;
#pragma unroll
    for (int k = 0; k < 16; ++k) {
        float4 a = *(const float4*)(xr + 4 * k);
        float4 c = *(const float4*)(yr + 4 * k);
        float d0 = a.x - c.x, d1 = a.y - c.y, d2 = a.z - c.z, d3 = a.w - c.w;
        acc += d0 * d0 + d1 * d1 + d2 * d2 + d3 * d3;
    }
    const int i = i0 + ti, j = j0 + tj;
    const int r = i + j, g = r >> 2, rs = r & 3, j2 = j >> 1, p = j & 1;
    dd2[(((((size_t)b << 8) | g) << 8) | j2) * 8 + rs * 2 + p] =
        __float2half(sqrtf(acc));
}

__device__ __forceinline__ float dpp_shr1(float x) {
    int v = __builtin_amdgcn_update_dpp(0x7f800000, __float_as_int(x),
                                        0x138 /*WAVE_SHR1*/, 0xf, 0xf, false);
    return __int_as_float(v);
}

__device__ __forceinline__ float vmin3(float a, float b, float c) {
    float r; asm("v_min3_f32 %0, %1, %2, %3" : "=v"(r) : "v"(a), "v"(b), "v"(c)); return r;
}
__device__ __forceinline__ float vmed3(float a, float b, float c) {
    float r; asm("v_med3_f32 %0, %1, %2, %3" : "=v"(r) : "v"(a), "v"(b), "v"(c)); return r;
}
__device__ __forceinline__ float vmax3(float a, float b, float c) {
    float r; asm("v_max3_f32 %0, %1, %2, %3" : "=v"(r) : "v"(a), "v"(b), "v"(c)); return r;
}

#if __has_builtin(__builtin_amdgcn_exp2f)
#define EXP2(x) __builtin_amdgcn_exp2f(x)
#else
#define EXP2(x) exp2f(x)
#endif
#if __has_builtin(__builtin_amdgcn_logf)
#define LOG2(x) __builtin_amdgcn_logf(x)
#else
#define LOG2(x) log2f(x)
#endif

__device__ __forceinline__ float2 h2f(unsigned u) {
    union { unsigned u; __half2 h; } cv; cv.u = u;
    return __half22float2(cv.h);
}

// Phase 2 (R10's proven-passing kernel, probe removed): staggered soft-DTW,
// fp16 group-packed d-transport, 4 x global_load_dwordx4 per chunk into
// named uint32x4 quads (3 buffers, 2 chunks ahead), exact counted vmcnt.
__global__ __launch_bounds__(256, 1) void sdtw_h4_kernel(
    const __half* __restrict__ dd2, float* __restrict__ out)
{
    const int b = blockIdx.x;
    const int tid = threadIdx.x;
    const int w = tid >> 6;
    const int lane = tid & 63;

    for (int q = tid; q < N_; q += 256) {
        out[b * N_ + q] = (float)q;
        out[B_ * N_ + b * N_ + q] = (float)q;
    }

    __shared__ __align__(16) float ring[WV + 1][RING];
    for (int q = tid; q < (WV + 1) * RING; q += 256)
        (&ring[0][0])[q] = (q == 0) ? 0.0f : BIGF;
    asm volatile("s_waitcnt vmcnt(0)");  // drain path stores: clean vmcnt
    __syncthreads();

    const float C1 = 14.4269504089f;    // (1/gamma)*log2(e)
    const float C2 = -0.069314718056f;  // -gamma*ln(2)
    const int c0w = DC0 * w;
    const int s0w = 128 * w + 2;
    const bool l0 = (lane == 0);
    const bool l63 = (lane == 63);
    const float* ringR = ring[w];
    float* ringW = ring[w + 1];
    // byte addr of group cell gi of chunk lc: wbase + (4*lc+gi)*4096
    const uint64_t wbase = (uint64_t)dd2 + ((uint64_t)b << 20)
                         + (uint64_t)(64 * w + lane) * 16
                         + ((uint64_t)(32 * w) << 12);
    float res = 0.0f;

    unsigned u0 = (unsigned)(-(2 * lane));
    float rA0 = BIGF, rB0 = BIGF, rA1 = BIGF;
    float lnL = BIGF, ldL = BIGF;

    uint32x4 qb0_0{}, qb0_1{}, qb0_2{}, qb0_3{};
    uint32x4 qb1_0{}, qb1_1{}, qb1_2{}, qb1_3{};
    uint32x4 qb2_0{}, qb2_1{}, qb2_2{}, qb2_3{};

#define ISSUE4(lcn_, b_)                                                    \
    {                                                                       \
        const uint64_t g0_ = wbase + ((uint64_t)((lcn_) * 4) << 12);        \
        asm volatile("global_load_dwordx4 %0, %1, off"                      \
                     : "=v"(qb##b_##_0) : "v"(g0_));                        \
        asm volatile("global_load_dwordx4 %0, %1, off"                      \
                     : "=v"(qb##b_##_1) : "v"(g0_ + 4096));                 \
        asm volatile("global_load_dwordx4 %0, %1, off"                      \
                     : "=v"(qb##b_##_2) : "v"(g0_ + 8192));                 \
        asm volatile("global_load_dwordx4 %0, %1, off"                      \
                     : "=v"(qb##b_##_3) : "v"(g0_ + 12288));                \
    }

#define TIE4(b_)                                                            \
    asm volatile("" : "+v"(qb##b_##_0), "+v"(qb##b_##_1),                   \
                      "+v"(qb##b_##_2), "+v"(qb##b_##_3));

#define STEP(d0_, d1_, tt_, rrn_)                                           \
    {                                                                       \
        float m0  = vmin3(rA0, lnL, ldL);                                   \
        float md0 = vmed3(rA0, lnL, ldL);                                   \
        float mx0 = vmax3(rA0, lnL, ldL);                                   \
        float e0 = EXP2((m0 - md0) * C1);                                   \
        float f0 = EXP2((m0 - mx0) * C1);                                   \
        float r0 = fmaf(C2, LOG2(1.0f + e0 + f0), m0 + (d0_));              \
        float m1  = vmin3(rA1, rA0, rB0);                                   \
        float md1 = vmed3(rA1, rA0, rB0);                                   \
        float mx1 = vmax3(rA1, rA0, rB0);                                   \
        float e1 = EXP2((m1 - md1) * C1);                                   \
        float f1 = EXP2((m1 - mx1) * C1);                                   \
        float r1 = fmaf(C2, LOG2(1.0f + e1 + f1), m1 + (d1_));              \
        res = (u0 == 512u) ? r1 : res;                                      \
        u0 += 1u;                                                           \
        rB0 = rA0; rA0 = r0;                                                \
        ldL = lnL;                                                          \
        float sh = dpp_shr1(r1);                                            \
        lnL = l0 ? (rrn_) : sh;                                             \
        rA1 = r1;                                                           \
        if (l63) ringW[s0c + (tt_)] = r1;                                   \
    }

#define GBLOCK(b_, gi_, t0_, rA_, rB_, rC_, rD_)                            \
    {                                                                       \
        const float2 fa_ = h2f(qb##b_##_##gi_[0]);                          \
        const float2 fb_ = h2f(qb##b_##_##gi_[1]);                          \
        const float2 fc_ = h2f(qb##b_##_##gi_[2]);                          \
        const float2 fd_ = h2f(qb##b_##_##gi_[3]);                          \
        STEP(fa_.x, fa_.y, (t0_) + 0, rA_)                                  \
        STEP(fb_.x, fb_.y, (t0_) + 1, rB_)                                  \
        STEP(fc_.x, fc_.y, (t0_) + 2, rC_)                                  \
        STEP(fd_.x, fd_.y, (t0_) + 3, rD_)                                  \
    }

#define CHUNK(b_, b2_)                                                      \
    {                                                                       \
        const int s0c = s0w + lc * K_;                                      \
        if (lc + 2 < NCH) {                                                 \
            ISSUE4(lc + 2, b2_);                                            \
            asm volatile("s_waitcnt vmcnt(8)");                             \
        } else if (lc + 1 < NCH) {                                          \
            asm volatile("s_waitcnt vmcnt(4)");                             \
        } else {                                                            \
            asm volatile("s_waitcnt vmcnt(0)");                             \
        }                                                                   \
        TIE4(b_);                                                           \
        const float4 qr0 = *(const float4*)&ringR[s0c - 2];                 \
        const float4 qr1 = *(const float4*)&ringR[s0c + 2];                 \
        const float4 qr2 = *(const float4*)&ringR[s0c + 6];                 \
        const float4 qr3 = *(const float4*)&ringR[s0c + 10];                \
        const float2 qr4 = *(const float2*)&ringR[s0c + 14];                \
        const float rr0 = qr0.x, rr1 = qr0.y, rr2 = qr0.z, rr3 = qr0.w;     \
        const float rr4 = qr1.x, rr5 = qr1.y, rr6 = qr1.z, rr7 = qr1.w;     \
        const float rr8 = qr2.x, rr9 = qr2.y, rr10 = qr2.z, rr11 = qr2.w;   \
        const float rr12 = qr3.x, rr13 = qr3.y, rr14 = qr3.z, rr15 = qr3.w; \
        const float rr16 = qr4.x, rr17 = qr4.y;                             \
        if (lc == 0) {                                                      \
            lnL = l0 ? rr1 : BIGF;                                          \
            ldL = l0 ? rr0 : BIGF;                                          \
        }                                                                   \
        GBLOCK(b_, 0, 0,  rr2,  rr3,  rr4,  rr5)                            \
        GBLOCK(b_, 1, 4,  rr6,  rr7,  rr8,  rr9)                            \
        GBLOCK(b_, 2, 8,  rr10, rr11, rr12, rr13)                           \
        GBLOCK(b_, 3, 12, rr14, rr15, rr16, rr17)                           \
    }

    if (w == 0) { ISSUE4(0, 0); ISSUE4(1, 1); }  // wave-0 prologue

    for (int c = 0; c < CTOT; ++c) {
        const int lc = c - c0w;
        if (lc >= 0 && lc < NCH) {
            switch (lc % 3) {
                case 0: { CHUNK(0, 2) } break;
                case 1: { CHUNK(1, 0) } break;
                default: { CHUNK(2, 1) } break;
            }
        } else if (lc == -2) {
            ISSUE4(0, 0);
        } else if (lc == -1) {
            ISSUE4(1, 1);
        }
        // LDS-only drain + barrier (d-loads stay in flight)
        asm volatile("s_waitcnt lgkmcnt(0)" ::: "memory");
        __builtin_amdgcn_s_barrier();
    }
#undef CHUNK
#undef GBLOCK
#undef STEP
#undef TIE4
#undef ISSUE4

    // R[512][512] captured by wave 3 / lane 63 at i1 == 512
    if (w == WV - 1 && l63) out[2 * B_ * N_ + b] = res;
}

extern "C" void kernel_launch(void* const* d_in, const int* in_sizes, int n_in,
                              void* d_out, int out_size, void* d_ws, size_t ws_size,
                              hipStream_t stream) {
    const float* x = (const float*)d_in[0];
    const float* y = (const float*)d_in[1];
    float* out = (float*)d_out;
    __half* dd2 = (__half*)d_ws;  // 4 MB fp16 packed table (ws >= 8 MB)

    dim3 g1(N_ / 16, N_ / 16, B_);
    dist_h_kernel<<<g1, 256, 0, stream>>>(x, y, dd2);
    sdtw_h4_kernel<<<B_, 256, 0, stream>>>(dd2, out);
}

// Round 16
// 116.931 us; speedup vs baseline: 4.0344x; 1.0336x over previous
//
#include <hip/hip_runtime.h>
#include <hip/hip_fp16.h>
#include <math.h>
#include <stdint.h>

#define B_ 4
#define N_ 512
#define D_ 64
#define NDIAG (2 * N_ - 1)   // 1023 diagonal rows of D
#define WV 4                 // consumer waves (+ WV producer waves)
#define K_ 16                // diagonals per chunk (between barriers)
#define DC0 9                // chunk stagger between adjacent consumer waves
#define NCH 40               // chunks per wave
#define CTOT (DC0 * (WV - 1) + NCH)  // 67 intervals
#define RING 1028
#define BIGF 1e30f           // finite border sentinel (absorbs garbage d)

typedef unsigned int uint32x4 __attribute__((ext_vector_type(4)));

// Phase 1: D in FP16, group-packed: half idx = ((b*256+g)*256 + j2)*8 + rs*2+p
// (r=i+j, g=r/4, rs=r%4, j2=j/2, p=j%2) -> 16B lane-load = 4 rows x 2 cols.
__global__ __launch_bounds__(256) void dist_h_kernel(
    const float* __restrict__ x, const float* __restrict__ y,
    __half* __restrict__ dd2)
{
    const int b = blockIdx.z;
    const int i0 = blockIdx.y * 16;
    const int j0 = blockIdx.x * 16;
    __shared__ float xs[16 * 68];
    __shared__ float ys[16 * 68];
    const int t = threadIdx.x;
    const int lr = t >> 4;
    const int lc = t & 15;
    const float4* xsrc = (const float4*)(x + (((size_t)b * N_) + i0 + lr) * D_);
    const float4* ysrc = (const float4*)(y + (((size_t)b * N_) + j0 + lr) * D_);
    *(float4*)(&xs[lr * 68 + lc * 4]) = xsrc[lc];
    *(float4*)(&ys[lr * 68 + lc * 4]) = ysrc[lc];
    __syncthreads();

    const int ti = t >> 4, tj = t & 15;
    const float* xr = &xs[ti * 68];
    const float* yr = &ys[tj * 68];
    float acc = 0.f;
#pragma unroll
    for (int k = 0; k < 16; ++k) {
        float4 a = *(const float4*)(xr + 4 * k);
        float4 c = *(const float4*)(yr + 4 * k);
        float d0 = a.x - c.x, d1 = a.y - c.y, d2 = a.z - c.z, d3 = a.w - c.w;
        acc += d0 * d0 + d1 * d1 + d2 * d2 + d3 * d3;
    }
    const int i = i0 + ti, j = j0 + tj;
    const int r = i + j, g = r >> 2, rs = r & 3, j2 = j >> 1, p = j & 1;
    dd2[(((((size_t)b << 8) | g) << 8) | j2) * 8 + rs * 2 + p] =
        __float2half(sqrtf(acc));
}

__device__ __forceinline__ float dpp_shr1(float x) {
    int v = __builtin_amdgcn_update_dpp(0x7f800000, __float_as_int(x),
                                        0x138 /*WAVE_SHR1*/, 0xf, 0xf, false);
    return __int_as_float(v);
}
__device__ __forceinline__ float vmin3(float a, float b, float c) {
    float r; asm("v_min3_f32 %0, %1, %2, %3" : "=v"(r) : "v"(a), "v"(b), "v"(c)); return r;
}
__device__ __forceinline__ float vmed3(float a, float b, float c) {
    float r; asm("v_med3_f32 %0, %1, %2, %3" : "=v"(r) : "v"(a), "v"(b), "v"(c)); return r;
}
__device__ __forceinline__ float vmax3(float a, float b, float c) {
    float r; asm("v_max3_f32 %0, %1, %2, %3" : "=v"(r) : "v"(a), "v"(b), "v"(c)); return r;
}
#if __has_builtin(__builtin_amdgcn_exp2f)
#define EXP2(x) __builtin_amdgcn_exp2f(x)
#else
#define EXP2(x) exp2f(x)
#endif
#if __has_builtin(__builtin_amdgcn_logf)
#define LOG2(x) __builtin_amdgcn_logf(x)
#else
#define LOG2(x) log2f(x)
#endif
__device__ __forceinline__ float2 h2f(unsigned u) {
    union { unsigned u; __half2 h; } cv; cv.u = u;
    return __half22float2(cv.h);
}

// Phase 2: producer/consumer, hazard-free transport. Consumers (wid 0-3):
// ZERO VMEM in loop — d from LDS double-buffer, ring handoff as in R15.
// Producers (wid 4-7): PLAIN C++ global loads + PLAIN LDS stores — the
// compiler inserts the vmcnt before each ds_write (correct by construction;
// R13/R14's asm-load + manual-vmcnt + spill interaction is eliminated).
// Producer stalls hide behind the consumer wave on the same SIMD.
__global__ __launch_bounds__(512, 1) void sdtw_pc3_kernel(
    const __half* __restrict__ dd2, float* __restrict__ out)
{
    const int b = blockIdx.x;
    const int tid = threadIdx.x;
    const int wid = tid >> 6;
    const int lane = tid & 63;
    const bool isCons = (wid < WV);
    const int w = isCons ? wid : wid - WV;

    // deterministic monotone paths (512 threads cover N_=512 exactly)
    out[b * N_ + tid] = (float)tid;
    out[B_ * N_ + b * N_ + tid] = (float)tid;

    __shared__ __align__(16) float ring[WV + 1][RING];          // 20.6 KB
    __shared__ __align__(16) __half pbuf[WV][2][K_ * 128];      // 32 KB
    for (int q = tid; q < (WV + 1) * RING; q += 512)
        (&ring[0][0])[q] = (q == 0) ? 0.0f : BIGF;

    const float C1 = 14.4269504089f;    // (1/gamma)*log2(e)
    const float C2 = -0.069314718056f;  // -gamma*ln(2)
    const int c0w = DC0 * w;
    const int s0w = 128 * w + 2;
    const bool l0 = (lane == 0);
    const bool l63 = (lane == 63);
    const float* ringR = ring[w];
    float* ringW = ring[w + 1];
    // global byte addr of group cell gi of chunk lc: wbase + (4*lc+gi)*4096
    const uint64_t wbase = (uint64_t)dd2 + ((uint64_t)b << 20)
                         + (uint64_t)(64 * w + lane) * 16
                         + ((uint64_t)(32 * w) << 12);

    // w=0 producer prologue: stage chunk 0 with plain loads/stores; the
    // __syncthreads below waits vmcnt+lgkm for all waves -> sealed.
    if (wid == WV) {
        const uint32x4 v0 = *(const uint32x4*)(wbase);
        const uint32x4 v1 = *(const uint32x4*)(wbase + 4096);
        const uint32x4 v2 = *(const uint32x4*)(wbase + 8192);
        const uint32x4 v3 = *(const uint32x4*)(wbase + 12288);
        char* dst = (char*)&pbuf[0][0][0] + lane * 16;
        *(uint32x4*)(dst)        = v0;
        *(uint32x4*)(dst + 1024) = v1;
        *(uint32x4*)(dst + 2048) = v2;
        *(uint32x4*)(dst + 3072) = v3;
    }
    __syncthreads();

    unsigned u0 = (unsigned)(-(2 * lane));
    float rA0 = BIGF, rB0 = BIGF, rA1 = BIGF;
    float lnL = BIGF, ldL = BIGF;
    float res = 0.0f;

#define STEP(d0_, d1_, tt_, rrn_)                                           \
    {                                                                       \
        float m0  = vmin3(rA0, lnL, ldL);                                   \
        float md0 = vmed3(rA0, lnL, ldL);                                   \
        float mx0 = vmax3(rA0, lnL, ldL);                                   \
        float e0 = EXP2((m0 - md0) * C1);                                   \
        float f0 = EXP2((m0 - mx0) * C1);                                   \
        float r0 = fmaf(C2, LOG2(1.0f + e0 + f0), m0 + (d0_));              \
        float m1  = vmin3(rA1, rA0, rB0);                                   \
        float md1 = vmed3(rA1, rA0, rB0);                                   \
        float mx1 = vmax3(rA1, rA0, rB0);                                   \
        float e1 = EXP2((m1 - md1) * C1);                                   \
        float f1 = EXP2((m1 - mx1) * C1);                                   \
        float r1 = fmaf(C2, LOG2(1.0f + e1 + f1), m1 + (d1_));              \
        res = (u0 == 512u) ? r1 : res;                                      \
        u0 += 1u;                                                           \
        rB0 = rA0; rA0 = r0;                                                \
        ldL = lnL;                                                          \
        float sh = dpp_shr1(r1);                                            \
        lnL = l0 ? (rrn_) : sh;                                             \
        rA1 = r1;                                                           \
        if (l63) ringW[s0c + (tt_)] = r1;                                   \
    }
#define GBLOCK(q_, gi_, rA_, rB_, rC_, rD_)                                 \
    {                                                                       \
        const float2 fa_ = h2f((q_)[0]);                                    \
        const float2 fb_ = h2f((q_)[1]);                                    \
        const float2 fc_ = h2f((q_)[2]);                                    \
        const float2 fd_ = h2f((q_)[3]);                                    \
        STEP(fa_.x, fa_.y, 4 * (gi_) + 0, rA_)                              \
        STEP(fb_.x, fb_.y, 4 * (gi_) + 1, rB_)                              \
        STEP(fc_.x, fc_.y, 4 * (gi_) + 2, rC_)                              \
        STEP(fd_.x, fd_.y, 4 * (gi_) + 3, rD_)                              \
    }

    for (int c = 0; c < CTOT; ++c) {
        const int lc = c - c0w;
        if (isCons) {
            if (lc >= 0 && lc < NCH) {
                const int s0c = s0w + lc * K_;
                // d-chunk from LDS (staged by producer, sealed by barrier)
                const char* cb = (const char*)&pbuf[w][lc & 1][0] + lane * 16;
                const uint32x4 cq0 = *(const uint32x4*)(cb);
                const uint32x4 cq1 = *(const uint32x4*)(cb + 1024);
                const uint32x4 cq2 = *(const uint32x4*)(cb + 2048);
                const uint32x4 cq3 = *(const uint32x4*)(cb + 3072);
                const float4 p0 = *(const float4*)&ringR[s0c - 2];
                const float4 p1 = *(const float4*)&ringR[s0c + 2];
                const float4 p2 = *(const float4*)&ringR[s0c + 6];
                const float4 p3 = *(const float4*)&ringR[s0c + 10];
                const float2 p4 = *(const float2*)&ringR[s0c + 14];
                const float rr0 = p0.x, rr1 = p0.y, rr2 = p0.z, rr3 = p0.w;
                const float rr4 = p1.x, rr5 = p1.y, rr6 = p1.z, rr7 = p1.w;
                const float rr8 = p2.x, rr9 = p2.y, rr10 = p2.z, rr11 = p2.w;
                const float rr12 = p3.x, rr13 = p3.y, rr14 = p3.z, rr15 = p3.w;
                const float rr16 = p4.x, rr17 = p4.y;
                if (lc == 0) {
                    lnL = l0 ? rr1 : BIGF;
                    ldL = l0 ? rr0 : BIGF;
                }
                GBLOCK(cq0, 0, rr2,  rr3,  rr4,  rr5)
                GBLOCK(cq1, 1, rr6,  rr7,  rr8,  rr9)
                GBLOCK(cq2, 2, rr10, rr11, rr12, rr13)
                GBLOCK(cq3, 3, rr14, rr15, rr16, rr17)
            }
        } else {
            // producer: stage chunk wc = lc+1 for interval c+1. Plain loads
            // and stores; compiler inserts the vmcnt before the ds_writes.
            const int wc = lc + 1;
            if (wc >= 0 && wc < NCH) {
                const uint64_t g0 = wbase + ((uint64_t)(wc * 4) << 12);
                const uint32x4 v0 = *(const uint32x4*)(g0);
                const uint32x4 v1 = *(const uint32x4*)(g0 + 4096);
                const uint32x4 v2 = *(const uint32x4*)(g0 + 8192);
                const uint32x4 v3 = *(const uint32x4*)(g0 + 12288);
                char* dst = (char*)&pbuf[w][wc & 1][0] + lane * 16;
                *(uint32x4*)(dst)        = v0;
                *(uint32x4*)(dst + 1024) = v1;
                *(uint32x4*)(dst + 2048) = v2;
                *(uint32x4*)(dst + 3072) = v3;
            }
        }
        // drain LDS (ring + producer staging) then barrier, every interval
        asm volatile("s_waitcnt lgkmcnt(0)" ::: "memory");
        __builtin_amdgcn_s_barrier();
    }
#undef GBLOCK
#undef STEP

    // R[512][512] captured by consumer wave 3 / lane 63 at i1 == 512
    if (wid == WV - 1 && l63) out[2 * B_ * N_ + b] = res;
}

extern "C" void kernel_launch(void* const* d_in, const int* in_sizes, int n_in,
                              void* d_out, int out_size, void* d_ws, size_t ws_size,
                              hipStream_t stream) {
    const float* x = (const float*)d_in[0];
    const float* y = (const float*)d_in[1];
    float* out = (float*)d_out;
    __half* dd2 = (__half*)d_ws;  // 4 MB fp16 packed table (ws >= 8 MB)

    dim3 g1(N_ / 16, N_ / 16, B_);
    dist_h_kernel<<<g1, 256, 0, stream>>>(x, y, dd2);
    sdtw_pc3_kernel<<<B_, 512, 0, stream>>>(dd2, out);
}